// Round 1
// baseline (9852.107 us; speedup 1.0000x reference)
//
#include <hip/hip_runtime.h>
#include <hip/hip_bf16.h>
#include <hip/hip_fp16.h>

#define N_RES   4096
#define MAXD    4608
#define IN_DIM  1024
#define T_STEPS 128
#define B_SZ    128
#define KPRE    3072   // 3 * 1024 (hi*hi | hi*lo | lo*hi)

typedef __attribute__((ext_vector_type(8))) short bf16x8;
typedef __attribute__((ext_vector_type(4))) float f32x4;

__device__ __forceinline__ short f2bf(float x) {
  union { float f; unsigned u; } v; v.f = x;
  unsigned r = v.u + 0x7fffu + ((v.u >> 16) & 1u);
  return (short)(r >> 16);
}
__device__ __forceinline__ float bf2f(short b) {
  union { float f; unsigned u; } v; v.u = ((unsigned)(unsigned short)b) << 16;
  return v.f;
}

__device__ __forceinline__ void gload16(const void* g, void* l) {
  __builtin_amdgcn_global_load_lds(
      (const __attribute__((address_space(1))) void*)g,
      (__attribute__((address_space(3))) void*)l,
      16, 0, 0);
}

// ---------------- zero output ----------------
__global__ void k_zero(float4* p, int n4) {
  int stride = gridDim.x * blockDim.x;
  for (int i = blockIdx.x * blockDim.x + threadIdx.x; i < n4; i += stride)
    p[i] = float4{0.f, 0.f, 0.f, 0.f};
}

// ---------------- init state from state0 ----------------
__global__ void k_init_state(const float* __restrict__ s0,
                             float* __restrict__ sF, short* __restrict__ sB) {
  int i = blockIdx.x * 256 + threadIdx.x;   // 128*4096 total
  int m = i >> 12, n = i & 4095;
  float v = s0[m * MAXD + n];
  sF[i] = v;
  sB[i] = f2bf(v);
}

// ---------------- transpose W_res -> bf16 [n][k] ----------------
__global__ void k_wres_t(const float* __restrict__ W, short* __restrict__ bt) {
  __shared__ float tile[64][65];
  int k0 = blockIdx.y * 64, n0 = blockIdx.x * 64;
  int tx = threadIdx.x & 63, ty = threadIdx.x >> 6;   // 256 thr
  #pragma unroll
  for (int r = 0; r < 64; r += 4)
    tile[r + ty][tx] = W[(long)(k0 + r + ty) * N_RES + n0 + tx];
  __syncthreads();
  #pragma unroll
  for (int r = 0; r < 64; r += 4)
    bt[(long)(n0 + r + ty) * N_RES + k0 + tx] = f2bf(tile[tx][r + ty]);
}

// ---------------- build B2 = [Whi | Wlo | Whi] rows of [W_in;W_gate] ----------------
__global__ void k_build_b2(const float* __restrict__ Win,
                           const float* __restrict__ Wg, short* __restrict__ B2) {
  int r = blockIdx.x;   // 16384 rows
  const float* src = (r < N_RES) ? (Win + (long)r * IN_DIM)
                                 : (Wg + (long)(r - N_RES) * IN_DIM);
  short* dst = B2 + (long)r * KPRE;
  for (int c = threadIdx.x; c < IN_DIM; c += 256) {
    float x = src[c];
    short h = f2bf(x);
    short l = f2bf(x - bf2f(h));
    dst[c] = h; dst[IN_DIM + c] = l; dst[2 * IN_DIM + c] = h;
  }
}

// ---------------- build A2 chunk = [Xhi | Xhi | Xlo] ----------------
__global__ void k_build_a2(const float* __restrict__ x, short* __restrict__ A2, int t0) {
  int r = blockIdx.x;   // Tc*128 rows
  const float* src = x + (long)(t0 * B_SZ + r) * IN_DIM;
  short* dst = A2 + (long)r * KPRE;
  for (int c = threadIdx.x; c < IN_DIM; c += 256) {
    float v = src[c];
    short h = f2bf(v);
    short l = f2bf(v - bf2f(h));
    dst[c] = h; dst[IN_DIM + c] = h; dst[2 * IN_DIM + c] = l;
  }
}

// ---------------- precompute GEMM: C = A2 @ B2^T, epilogue -> ip(fp16), gates(sigmoid,fp16) ----------------
__global__ __launch_bounds__(256) void k_gemm_pre(
    const short* __restrict__ A2, const short* __restrict__ B2,
    _Float16* __restrict__ ip, _Float16* __restrict__ gates) {
  __shared__ short lA[128 * 64];
  __shared__ short lB[128 * 64];
  int tid = threadIdx.x, lane = tid & 63, wid = tid >> 6;
  int wm = wid >> 1, wn = wid & 1;
  long m0 = (long)blockIdx.y * 128, n0 = (long)blockIdx.x * 128;

  f32x4 acc[4][4] = {};
  for (int k0 = 0; k0 < KPRE; k0 += 64) {
    #pragma unroll
    for (int is = 0; is < 4; ++is) {
      int c = is * 4 + wid;                 // 16 chunks of 1024B each
      int row = c * 8 + (lane >> 3);
      int col = (lane & 7) * 8;
      gload16(A2 + (m0 + row) * KPRE + k0 + col, lA + c * 512);
      gload16(B2 + (n0 + row) * KPRE + k0 + col, lB + c * 512);
    }
    asm volatile("s_waitcnt vmcnt(0)" ::: "memory");
    __syncthreads();
    #pragma unroll
    for (int kk = 0; kk < 64; kk += 32) {
      bf16x8 aF[4], bF[4];
      #pragma unroll
      for (int i = 0; i < 4; ++i)
        aF[i] = *(const bf16x8*)&lA[(wm * 64 + i * 16 + (lane & 15)) * 64 + kk + (lane >> 4) * 8];
      #pragma unroll
      for (int j = 0; j < 4; ++j)
        bF[j] = *(const bf16x8*)&lB[(wn * 64 + j * 16 + (lane & 15)) * 64 + kk + (lane >> 4) * 8];
      #pragma unroll
      for (int i = 0; i < 4; ++i)
        #pragma unroll
        for (int j = 0; j < 4; ++j)
          acc[i][j] = __builtin_amdgcn_mfma_f32_16x16x32_bf16(aF[i], bF[j], acc[i][j], 0, 0, 0);
    }
    __syncthreads();
  }
  #pragma unroll
  for (int i = 0; i < 4; ++i)
    #pragma unroll
    for (int j = 0; j < 4; ++j)
      #pragma unroll
      for (int q = 0; q < 4; ++q) {
        long m = m0 + wm * 64 + i * 16 + (lane >> 4) * 4 + q;
        long n = n0 + wn * 64 + j * 16 + (lane & 15);
        float v = acc[i][j][q];
        if (n < N_RES) {
          ip[m * N_RES + n] = (_Float16)v;
        } else {
          gates[m * 12288 + (n - N_RES)] = (_Float16)(1.f / (1.f + __expf(-v)));
        }
      }
}

// ---------------- per-step: res = prev_bf16 @ WresBT^T, fused elementwise epilogue ----------------
__global__ __launch_bounds__(256) void k_step(
    const short* __restrict__ Abf,      // state bf16 (read buf)  [128][4096]
    const short* __restrict__ Bt,       // Wres^T bf16 [4096][4096]
    const _Float16* __restrict__ ip,    // + tloc*128*4096
    const _Float16* __restrict__ gates, // + tloc*128*12288
    float* __restrict__ sF,             // state fp32 [128][4096]
    short* __restrict__ sBw,            // state bf16 (write buf)
    float* __restrict__ out) {          // d_out + t*128*4608
  __shared__ short lA[128 * 64];
  __shared__ short lB[32 * 64];
  int tid = threadIdx.x, lane = tid & 63, wid = tid >> 6;
  int n0 = blockIdx.x * 32;

  f32x4 acc[2][2] = {};
  for (int k0 = 0; k0 < N_RES; k0 += 64) {
    #pragma unroll
    for (int is = 0; is < 4; ++is) {
      int c = is * 4 + wid;
      int row = c * 8 + (lane >> 3);
      int col = (lane & 7) * 8;
      gload16(Abf + (long)row * N_RES + k0 + col, lA + c * 512);
    }
    {
      int c = wid;
      int row = c * 8 + (lane >> 3);    // 0..31
      int col = (lane & 7) * 8;
      gload16(Bt + (long)(n0 + row) * N_RES + k0 + col, lB + c * 512);
    }
    asm volatile("s_waitcnt vmcnt(0)" ::: "memory");
    __syncthreads();
    #pragma unroll
    for (int kk = 0; kk < 64; kk += 32) {
      bf16x8 aF[2], bF[2];
      #pragma unroll
      for (int i = 0; i < 2; ++i)
        aF[i] = *(const bf16x8*)&lA[(wid * 32 + i * 16 + (lane & 15)) * 64 + kk + (lane >> 4) * 8];
      #pragma unroll
      for (int j = 0; j < 2; ++j)
        bF[j] = *(const bf16x8*)&lB[(j * 16 + (lane & 15)) * 64 + kk + (lane >> 4) * 8];
      #pragma unroll
      for (int i = 0; i < 2; ++i)
        #pragma unroll
        for (int j = 0; j < 2; ++j)
          acc[i][j] = __builtin_amdgcn_mfma_f32_16x16x32_bf16(aF[i], bF[j], acc[i][j], 0, 0, 0);
    }
    __syncthreads();
  }
  #pragma unroll
  for (int i = 0; i < 2; ++i)
    #pragma unroll
    for (int j = 0; j < 2; ++j)
      #pragma unroll
      for (int q = 0; q < 4; ++q) {
        int m = wid * 32 + i * 16 + (lane >> 4) * 4 + q;
        int n = n0 + j * 16 + (lane & 15);
        float res = acc[i][j][q];
        long idx = (long)m * N_RES + n;
        float prev = sF[idx];
        float ipv = (float)ip[idx];
        const _Float16* grow = gates + (long)m * 12288 + n;
        float ig = (float)grow[0];
        float fg = (float)grow[4096];
        float og = (float)grow[8192];
        float s = 0.9f * (fg * prev) + 0.1f * tanhf(ig * (ipv + res));
        s = og * s;
        if (s > 0.5f) s -= 0.5f;
        out[(long)m * MAXD + n] = s;
        sF[idx] = s;
        sBw[idx] = f2bf(s);
      }
}

extern "C" void kernel_launch(void* const* d_in, const int* in_sizes, int n_in,
                              void* d_out, int out_size, void* d_ws, size_t ws_size,
                              hipStream_t stream) {
  const float* x      = (const float*)d_in[0];
  const float* state0 = (const float*)d_in[1];
  const float* W_res  = (const float*)d_in[2];
  const float* W_in   = (const float*)d_in[3];
  const float* W_gate = (const float*)d_in[4];
  float* out = (float*)d_out;
  char* ws = (char*)d_ws;

  size_t off = 0;
  short* WresBT = (short*)(ws + off); off += (size_t)N_RES * N_RES * 2;       // 33.6 MB
  short* B2     = (short*)(ws + off); off += (size_t)16384 * KPRE * 2;        // 100.7 MB
  float* sF     = (float*)(ws + off); off += (size_t)B_SZ * N_RES * 4;        // 2 MB
  short* sB0    = (short*)(ws + off); off += (size_t)B_SZ * N_RES * 2;        // 1 MB
  short* sB1    = (short*)(ws + off); off += (size_t)B_SZ * N_RES * 2;        // 1 MB
  size_t fixed = off;
  size_t per = (size_t)B_SZ * KPRE * 2 + (size_t)B_SZ * N_RES * 2 + (size_t)B_SZ * 12288 * 2;

  int Tc = T_STEPS;
  while (Tc > 1 && fixed + (size_t)Tc * per > ws_size) Tc >>= 1;

  short*     A2  = (short*)(ws + fixed);
  _Float16*  ipb = (_Float16*)(ws + fixed + (size_t)Tc * B_SZ * KPRE * 2);
  _Float16*  gtb = (_Float16*)(ws + fixed + (size_t)Tc * B_SZ * KPRE * 2
                               + (size_t)Tc * B_SZ * N_RES * 2);

  // zero entire output (covers the MAX_DIM-N padding columns)
  int n4 = (T_STEPS * B_SZ * MAXD) / 4;
  k_zero<<<2048, 256, 0, stream>>>((float4*)out, n4);
  k_init_state<<<(B_SZ * N_RES) / 256, 256, 0, stream>>>(state0, sF, sB0);
  k_wres_t<<<dim3(64, 64), 256, 0, stream>>>(W_res, WresBT);
  k_build_b2<<<16384, 256, 0, stream>>>(W_in, W_gate, B2);

  for (int t0 = 0; t0 < T_STEPS; t0 += Tc) {
    k_build_a2<<<Tc * B_SZ, 256, 0, stream>>>(x, A2, t0);
    k_gemm_pre<<<dim3(128, Tc), 256, 0, stream>>>(A2, B2, ipb, gtb);
    for (int tl = 0; tl < Tc; ++tl) {
      int t = t0 + tl;
      const short* Ar = (t & 1) ? sB1 : sB0;
      short*       Aw = (t & 1) ? sB0 : sB1;
      k_step<<<N_RES / 32, 256, 0, stream>>>(
          Ar, WresBT,
          ipb + (size_t)tl * B_SZ * N_RES,
          gtb + (size_t)tl * B_SZ * 12288,
          sF, Aw,
          out + (size_t)t * B_SZ * MAXD);
    }
  }
}

// Round 2
// 6551.313 us; speedup vs baseline: 1.5038x; 1.5038x over previous
//
#include <hip/hip_runtime.h>
#include <hip/hip_bf16.h>
#include <hip/hip_fp16.h>

#define N_RES   4096
#define MAXD    4608
#define IN_DIM  1024
#define T_STEPS 128
#define B_SZ    128
#define KPRE    3072   // 3 * 1024 (hi*hi | hi*lo | lo*hi)

typedef __attribute__((ext_vector_type(8))) short bf16x8;
typedef __attribute__((ext_vector_type(4))) float f32x4;

__device__ __forceinline__ short f2bf(float x) {
  union { float f; unsigned u; } v; v.f = x;
  unsigned r = v.u + 0x7fffu + ((v.u >> 16) & 1u);
  return (short)(r >> 16);
}
__device__ __forceinline__ float bf2f(short b) {
  union { float f; unsigned u; } v; v.u = ((unsigned)(unsigned short)b) << 16;
  return v.f;
}

__device__ __forceinline__ void gload16(const void* g, void* l) {
  __builtin_amdgcn_global_load_lds(
      (const __attribute__((address_space(1))) void*)g,
      (__attribute__((address_space(3))) void*)l,
      16, 0, 0);
}

// ---------------- zero ONLY the padding columns [4096,4608) ----------------
__global__ void k_zero_pad(float* __restrict__ out) {
  int row = blockIdx.x;            // 16384 rows (T*B)
  int t = threadIdx.x;             // 128 threads * float4 = 512 cols
  *(float4*)(out + (size_t)row * MAXD + N_RES + t * 4) = float4{0.f, 0.f, 0.f, 0.f};
}

// ---------------- init state from state0 ----------------
__global__ void k_init_state(const float* __restrict__ s0,
                             float* __restrict__ sF, short* __restrict__ sB) {
  int i = blockIdx.x * 256 + threadIdx.x;   // 128*4096 total
  int m = i >> 12, n = i & 4095;
  float v = s0[m * MAXD + n];
  sF[i] = v;
  sB[i] = f2bf(v);
}

// ---------------- transpose W_res -> bf16 [n][k] ----------------
__global__ void k_wres_t(const float* __restrict__ W, short* __restrict__ bt) {
  __shared__ float tile[64][65];
  int k0 = blockIdx.y * 64, n0 = blockIdx.x * 64;
  int tx = threadIdx.x & 63, ty = threadIdx.x >> 6;   // 256 thr
  #pragma unroll
  for (int r = 0; r < 64; r += 4)
    tile[r + ty][tx] = W[(long)(k0 + r + ty) * N_RES + n0 + tx];
  __syncthreads();
  #pragma unroll
  for (int r = 0; r < 64; r += 4)
    bt[(long)(n0 + r + ty) * N_RES + k0 + tx] = f2bf(tile[tx][r + ty]);
}

// ---------------- build B2 = [Whi | Wlo | Whi] rows of [W_in;W_gate] ----------------
__global__ void k_build_b2(const float* __restrict__ Win,
                           const float* __restrict__ Wg, short* __restrict__ B2) {
  int r = blockIdx.x;   // 16384 rows
  const float* src = (r < N_RES) ? (Win + (long)r * IN_DIM)
                                 : (Wg + (long)(r - N_RES) * IN_DIM);
  short* dst = B2 + (long)r * KPRE;
  for (int c = threadIdx.x; c < IN_DIM; c += 256) {
    float x = src[c];
    short h = f2bf(x);
    short l = f2bf(x - bf2f(h));
    dst[c] = h; dst[IN_DIM + c] = l; dst[2 * IN_DIM + c] = h;
  }
}

// ---------------- build A2 chunk = [Xhi | Xhi | Xlo] ----------------
__global__ void k_build_a2(const float* __restrict__ x, short* __restrict__ A2, int t0) {
  int r = blockIdx.x;   // Tc*128 rows
  const float* src = x + (long)(t0 * B_SZ + r) * IN_DIM;
  short* dst = A2 + (long)r * KPRE;
  for (int c = threadIdx.x; c < IN_DIM; c += 256) {
    float v = src[c];
    short h = f2bf(v);
    short l = f2bf(v - bf2f(h));
    dst[c] = h; dst[IN_DIM + c] = h; dst[2 * IN_DIM + c] = l;
  }
}

// ---------------- precompute GEMM: C = A2 @ B2^T ----------------
// 128x128 tile, BK=64, grouped raster (GROUP_M=32), XOR-swizzled LDS.
// LDS layout: linear dest from global_load_lds; source column pre-swizzled by
// colchunk ^= (row&7); reads XOR byte bits 4-6 with (row&7)<<4.
__global__ __launch_bounds__(256) void k_gemm_pre(
    const short* __restrict__ A2, const short* __restrict__ B2,
    _Float16* __restrict__ ip, _Float16* __restrict__ gates, int Mtiles) {
  __shared__ short lA[128 * 64];
  __shared__ short lB[128 * 64];
  int tid = threadIdx.x, lane = tid & 63, wid = tid >> 6;
  int wm = wid >> 1, wn = wid & 1;

  int bid = blockIdx.x;
  int GM = Mtiles < 32 ? Mtiles : 32;
  int grp = bid / (GM * 128);
  int gm0 = grp * GM;
  int rem = Mtiles - gm0; if (rem > GM) rem = GM;
  int loc = bid - grp * (GM * 128);
  int mt = gm0 + loc % rem;
  int nt = loc / rem;
  long m0 = (long)mt * 128, n0 = (long)nt * 128;

  // staging: chunk c = is*4+wid; row = c*8 + (lane>>3); row&7 == lane>>3
  int srcCol = ((lane & 7) ^ (lane >> 3)) * 8;   // shorts, pre-swizzled source col
  int rowLo = lane >> 3;

  f32x4 acc[4][4] = {};
  for (int k0 = 0; k0 < KPRE; k0 += 64) {
    #pragma unroll
    for (int is = 0; is < 4; ++is) {
      int c = is * 4 + wid;
      int row = c * 8 + rowLo;
      gload16(A2 + (m0 + row) * KPRE + k0 + srcCol, lA + c * 512);
      gload16(B2 + (n0 + row) * KPRE + k0 + srcCol, lB + c * 512);
    }
    asm volatile("s_waitcnt vmcnt(0)" ::: "memory");
    __syncthreads();
    #pragma unroll
    for (int kk = 0; kk < 64; kk += 32) {
      int colS = (kk + (lane >> 4) * 8) ^ ((lane & 7) << 3);   // swizzled read col
      bf16x8 aF[4], bF[4];
      #pragma unroll
      for (int i = 0; i < 4; ++i)
        aF[i] = *(const bf16x8*)&lA[(wm * 64 + i * 16 + (lane & 15)) * 64 + colS];
      #pragma unroll
      for (int j = 0; j < 4; ++j)
        bF[j] = *(const bf16x8*)&lB[(wn * 64 + j * 16 + (lane & 15)) * 64 + colS];
      #pragma unroll
      for (int i = 0; i < 4; ++i)
        #pragma unroll
        for (int j = 0; j < 4; ++j)
          acc[i][j] = __builtin_amdgcn_mfma_f32_16x16x32_bf16(aF[i], bF[j], acc[i][j], 0, 0, 0);
    }
    __syncthreads();
  }
  #pragma unroll
  for (int i = 0; i < 4; ++i)
    #pragma unroll
    for (int j = 0; j < 4; ++j)
      #pragma unroll
      for (int q = 0; q < 4; ++q) {
        long m = m0 + wm * 64 + i * 16 + (lane >> 4) * 4 + q;
        long n = n0 + wn * 64 + j * 16 + (lane & 15);
        float v = acc[i][j][q];
        if (n < N_RES) {
          ip[m * N_RES + n] = (_Float16)v;
        } else {
          gates[m * 12288 + (n - N_RES)] = (_Float16)(1.f / (1.f + __expf(-v)));
        }
      }
}

// ---------------- per-step GEMM: res = prev_bf16 @ WresBT^T + fused epilogue ----
// BM=64 x BN=32, grid (128 n-tiles, 2 m-halves) = 256 blocks (1/CU).
// BK=128, double-buffered LDS (48 KiB), 2-phase: stage(t+1) || compute(t).
__global__ __launch_bounds__(256) void k_step(
    const short* __restrict__ Abf,      // state bf16 (read buf)  [128][4096]
    const short* __restrict__ Bt,       // Wres^T bf16 [4096][4096]
    const _Float16* __restrict__ ip,    // + tloc*128*4096
    const _Float16* __restrict__ gates, // + tloc*128*12288
    float* __restrict__ sF,             // state fp32 [128][4096]
    short* __restrict__ sBw,            // state bf16 (write buf)
    float* __restrict__ out) {          // d_out + t*128*4608
  __shared__ short lA[2][64 * 128];
  __shared__ short lB[2][32 * 128];
  int tid = threadIdx.x, lane = tid & 63, wid = tid >> 6;
  int wm = wid >> 1, wn = wid & 1;            // wave tile: rows wm*32..+32, cols wn*16..+16
  int n0 = blockIdx.x * 32;
  int m0 = blockIdx.y * 64;

  f32x4 acc[2] = {};

  // stage K-tile kt into buffer b. Tiles: A 64x128 (1024 16B-chunks), B 32x128 (512).
  // chunk c: row = c>>4, source colchunk = (c&15) ^ (row&7); dest linear c*16B.
  #define STAGE(kt, b)                                                        \
    {                                                                         \
      int k0s = (kt) * 128;                                                   \
      _Pragma("unroll")                                                       \
      for (int it = 0; it < 4; ++it) {                                        \
        int cb = it * 256 + wid * 64;                                         \
        int c = cb + lane;                                                    \
        int row = c >> 4;                                                     \
        int cc = (c & 15) ^ (row & 7);                                        \
        gload16(Abf + (size_t)(m0 + row) * N_RES + k0s + cc * 8,              \
                &lA[b][cb * 8]);                                              \
      }                                                                       \
      _Pragma("unroll")                                                       \
      for (int it = 0; it < 2; ++it) {                                        \
        int cb = it * 256 + wid * 64;                                         \
        int c = cb + lane;                                                    \
        int row = c >> 4;                                                     \
        int cc = (c & 15) ^ (row & 7);                                        \
        gload16(Bt + (size_t)(n0 + row) * N_RES + k0s + cc * 8,               \
                &lB[b][cb * 8]);                                              \
      }                                                                       \
    }

  STAGE(0, 0);
  asm volatile("s_waitcnt vmcnt(0)" ::: "memory");
  __syncthreads();

  for (int kt = 0; kt < 32; ++kt) {
    int cur = kt & 1;
    if (kt < 31) STAGE(kt + 1, cur ^ 1);
    #pragma unroll
    for (int kk = 0; kk < 128; kk += 32) {
      int colS = (kk + (lane >> 4) * 8) ^ ((lane & 7) << 3);
      bf16x8 aF[2], bF;
      #pragma unroll
      for (int i = 0; i < 2; ++i)
        aF[i] = *(const bf16x8*)&lA[cur][(wm * 32 + i * 16 + (lane & 15)) * 128 + colS];
      bF = *(const bf16x8*)&lB[cur][(wn * 16 + (lane & 15)) * 128 + colS];
      #pragma unroll
      for (int i = 0; i < 2; ++i)
        acc[i] = __builtin_amdgcn_mfma_f32_16x16x32_bf16(aF[i], bF, acc[i], 0, 0, 0);
    }
    asm volatile("s_waitcnt vmcnt(0)" ::: "memory");
    __syncthreads();
  }
  #undef STAGE

  #pragma unroll
  for (int i = 0; i < 2; ++i)
    #pragma unroll
    for (int q = 0; q < 4; ++q) {
      int m = m0 + wm * 32 + i * 16 + (lane >> 4) * 4 + q;
      int n = n0 + wn * 16 + (lane & 15);
      float res = acc[i][q];
      long idx = (long)m * N_RES + n;
      float prev = sF[idx];
      float ipv = (float)ip[idx];
      const _Float16* grow = gates + (long)m * 12288 + n;
      float ig = (float)grow[0];
      float fg = (float)grow[4096];
      float og = (float)grow[8192];
      float s = 0.9f * (fg * prev) + 0.1f * tanhf(ig * (ipv + res));
      s = og * s;
      if (s > 0.5f) s -= 0.5f;
      out[(long)m * MAXD + n] = s;
      sF[idx] = s;
      sBw[idx] = f2bf(s);
    }
}

extern "C" void kernel_launch(void* const* d_in, const int* in_sizes, int n_in,
                              void* d_out, int out_size, void* d_ws, size_t ws_size,
                              hipStream_t stream) {
  const float* x      = (const float*)d_in[0];
  const float* state0 = (const float*)d_in[1];
  const float* W_res  = (const float*)d_in[2];
  const float* W_in   = (const float*)d_in[3];
  const float* W_gate = (const float*)d_in[4];
  float* out = (float*)d_out;
  char* ws = (char*)d_ws;

  size_t off = 0;
  short* WresBT = (short*)(ws + off); off += (size_t)N_RES * N_RES * 2;       // 33.6 MB
  short* B2     = (short*)(ws + off); off += (size_t)16384 * KPRE * 2;        // 100.7 MB
  float* sF     = (float*)(ws + off); off += (size_t)B_SZ * N_RES * 4;        // 2 MB
  short* sB0    = (short*)(ws + off); off += (size_t)B_SZ * N_RES * 2;        // 1 MB
  short* sB1    = (short*)(ws + off); off += (size_t)B_SZ * N_RES * 2;        // 1 MB
  size_t fixed = off;
  size_t per = (size_t)B_SZ * KPRE * 2 + (size_t)B_SZ * N_RES * 2 + (size_t)B_SZ * 12288 * 2;

  int Tc = T_STEPS;
  while (Tc > 1 && fixed + (size_t)Tc * per > ws_size) Tc >>= 1;

  short*     A2  = (short*)(ws + fixed);
  _Float16*  ipb = (_Float16*)(ws + fixed + (size_t)Tc * B_SZ * KPRE * 2);
  _Float16*  gtb = (_Float16*)(ws + fixed + (size_t)Tc * B_SZ * KPRE * 2
                               + (size_t)Tc * B_SZ * N_RES * 2);

  k_zero_pad<<<T_STEPS * B_SZ, 128, 0, stream>>>(out);
  k_init_state<<<(B_SZ * N_RES) / 256, 256, 0, stream>>>(state0, sF, sB0);
  k_wres_t<<<dim3(64, 64), 256, 0, stream>>>(W_res, WresBT);
  k_build_b2<<<16384, 256, 0, stream>>>(W_in, W_gate, B2);

  for (int t0 = 0; t0 < T_STEPS; t0 += Tc) {
    k_build_a2<<<Tc * B_SZ, 256, 0, stream>>>(x, A2, t0);
    k_gemm_pre<<<Tc * 128, 256, 0, stream>>>(A2, B2, ipb, gtb, Tc);
    for (int tl = 0; tl < Tc; ++tl) {
      int t = t0 + tl;
      const short* Ar = (t & 1) ? sB1 : sB0;
      short*       Aw = (t & 1) ? sB0 : sB1;
      k_step<<<dim3(N_RES / 32, 2), 256, 0, stream>>>(
          Ar, WresBT,
          ipb + (size_t)tl * B_SZ * N_RES,
          gtb + (size_t)tl * B_SZ * 12288,
          sF, Aw,
          out + (size_t)t * B_SZ * MAXD);
    }
  }
}